// Round 2
// baseline (2001.898 us; speedup 1.0000x reference)
//
#include <hip/hip_runtime.h>

#define N_SEQ 2048
#define S_LEN 4096
#define W_SEQ 64                               // u64 words per sequence (S/64)
#define TILE 64
#define T_TILES (N_SEQ / TILE)                 // 32
#define NBLK (T_TILES * (T_TILES + 1) / 2)     // 528 upper-triangle tiles
#define ENC_BLK 256                            // dedicated encoder blocks
#define TOTAL_BLK (NBLK + ENC_BLK)             // 784 <= 1024 resident capacity
#define ENC_WAVES (ENC_BLK * 4)                // 1024 encode waves
#define GROUPS 32                              // 64-row groups
#define WORDS_PER_GROUP (TILE * W_SEQ)         // 4096 u128 words per group
#define WPWG (WORDS_PER_GROUP / ENC_WAVES)     // 4 words per wave per group
#define CHUNK 16                               // words per LDS K-chunk
#define STRIDE 17                              // padded LDS row stride (conflict-free)

typedef float vfloat4 __attribute__((ext_vector_type(4)));

// ---------------- Single fused cooperative kernel ----------------
// Role split: bid < ENC_BLK  -> encoder (stream one-hot -> 2-bit planes, in
// row-group order, releasing done[g] per group; block 0 also preps zbuf).
//             bid >= ENC_BLK -> pair tile (spins on done[r] with s_sleep,
// then popcount-hamming + hyperbolic epilogue + ticket reduce).
// encode is HBM-DMA-bound, pairs is VALU-bound -> different pipes overlap;
// only the 32 tiles needing group 31 wait for the full encode.
__global__ __launch_bounds__(256, 4) void fused_kernel(
    const vfloat4* __restrict__ data, const float* __restrict__ table,
    const float* __restrict__ log_scale, ulonglong2* __restrict__ codes,
    float4* __restrict__ zbuf, double* __restrict__ acc,
    unsigned* __restrict__ done,               // [GROUPS+1]: group counters + zflag
    unsigned* __restrict__ ticket, float* __restrict__ out)
{
    __shared__ ulonglong2 As[TILE * STRIDE];
    __shared__ ulonglong2 Bs[TILE * STRIDE];
    __shared__ float wsum[4];

    const int bid = blockIdx.x;
    const int tid = threadIdx.x;

    if (bid < ENC_BLK) {
        // ---------------- encoder role ----------------
        if (bid == 0) {
            // z-prep: 2048 entries, 8 per thread
            for (int i = tid; i < N_SEQ; i += 256) {
                float vx = table[2 * i], vy = table[2 * i + 1];
                float n = sqrtf(vx * vx + vy * vy);
                float f = tanhf(n) / fmaxf(n, 1e-12f);
                float zx = vx * f, zy = vy * f;
                zbuf[i] = make_float4(zx, zy, 1.0f - (zx * zx + zy * zy), 0.0f);
            }
            __syncthreads();
            if (tid == 0)
                __hip_atomic_fetch_add(&done[GROUPS], 1u, __ATOMIC_RELEASE,
                                       __HIP_MEMORY_SCOPE_AGENT);
        }
        const int wid  = bid * 4 + (tid >> 6);   // 0..1023
        const int lane = tid & 63;
        // groups strictly in order: done[g]==ENC_WAVES implies groups <=g all written
        for (int g = 0; g < GROUPS; ++g) {
            const int W0 = g * WORDS_PER_GROUP + wid * WPWG;
            vfloat4 v[WPWG];
#pragma unroll
            for (int k = 0; k < WPWG; ++k)       // 4 outstanding 1KB wave-loads
                v[k] = __builtin_nontemporal_load(&data[(size_t)(W0 + k) * 64 + lane]);
#pragma unroll
            for (int k = 0; k < WPWG; ++k) {
                // tokens: 0->x 1->y 2->z 3->w => lo-plane = y|w, hi-plane = z|w
                unsigned long long lo = __ballot(v[k].y + v[k].w > 0.5f);
                unsigned long long hi = __ballot(v[k].z + v[k].w > 0.5f);
                if (lane == 0) { ulonglong2 e; e.x = lo; e.y = hi; codes[W0 + k] = e; }
            }
            if (lane == 0)                        // release: codes stores visible first
                __hip_atomic_fetch_add(&done[g], 1u, __ATOMIC_RELEASE,
                                       __HIP_MEMORY_SCOPE_AGENT);
        }
        return;
    }

    // ---------------- pair-tile role ----------------
    const int tb = bid - ENC_BLK;
    // triangle mapping: tb = r*(r+1)/2 + c, c <= r (i-tile = c, j-tile = r)
    int r = (int)((sqrtf(8.0f * (float)tb + 1.0f) - 1.0f) * 0.5f);
    while ((r + 1) * (r + 2) / 2 <= tb) ++r;
    while (r * (r + 1) / 2 > tb) --r;
    const int c = tb - r * (r + 1) / 2;
    const int i0 = c * TILE, j0 = r * TILE;

    // wait for both row-groups (r >= c and groups complete in order)
    if (tid == 0) {
        while (__hip_atomic_load(&done[r], __ATOMIC_ACQUIRE,
                                 __HIP_MEMORY_SCOPE_AGENT) < ENC_WAVES)
            __builtin_amdgcn_s_sleep(16);
    }
    __syncthreads();

    const int tx = tid & 15, ty = tid >> 4;
    // hoisted staging addresses: entry e = tid + p*256 -> row = e>>4, w = e&15
    const int srow = tid >> 4, sw = tid & 15;
    const ulonglong2* gA = codes + (size_t)(i0 + srow) * W_SEQ + sw;
    const ulonglong2* gB = codes + (size_t)(j0 + srow) * W_SEQ + sw;
    ulonglong2* lA = As + srow * STRIDE + sw;
    ulonglong2* lB = Bs + srow * STRIDE + sw;

    int mis[4][4];
#pragma unroll
    for (int k = 0; k < 4; ++k)
#pragma unroll
        for (int l = 0; l < 4; ++l) mis[k][l] = 0;

    for (int cc = 0; cc < W_SEQ / CHUNK; ++cc) {
#pragma unroll
        for (int p = 0; p < 4; ++p) {            // +16 rows per pass
            lA[p * 16 * STRIDE] = gA[(size_t)(p * 16) * W_SEQ + cc * CHUNK];
            lB[p * 16 * STRIDE] = gB[(size_t)(p * 16) * W_SEQ + cc * CHUNK];
        }
        __syncthreads();
#pragma unroll
        for (int w = 0; w < CHUNK; ++w) {
            ulonglong2 a[4], bb[4];
#pragma unroll
            for (int k = 0; k < 4; ++k) a[k] = As[(ty + 16 * k) * STRIDE + w];
#pragma unroll
            for (int l = 0; l < 4; ++l) bb[l] = Bs[(tx + 16 * l) * STRIDE + w];
#pragma unroll
            for (int k = 0; k < 4; ++k)
#pragma unroll
                for (int l = 0; l < 4; ++l)
                    mis[k][l] += __popcll((a[k].x ^ bb[l].x) | (a[k].y ^ bb[l].y));
        }
        __syncthreads();
    }

    // zbuf readiness (set ~at encode start; in practice never spins here)
    if (tid == 0) {
        while (__hip_atomic_load(&done[GROUPS], __ATOMIC_ACQUIRE,
                                 __HIP_MEMORY_SCOPE_AGENT) < 1u)
            __builtin_amdgcn_s_sleep(16);
    }
    __syncthreads();

    // fused epilogue: exact hamming, hyperbolic dist, symmetry-weighted sq-diff
    float scale = expf(log_scale[0]);
    const float inv_s = 1.0f / (float)S_LEN;
    float local = 0.0f;
#pragma unroll
    for (int k = 0; k < 4; ++k) {
        int i = i0 + ty + 16 * k;
        float4 zi = zbuf[i];
#pragma unroll
        for (int l = 0; l < 4; ++l) {
            int j = j0 + tx + 16 * l;
            float4 zj = zbuf[j];
            float ham = (float)mis[k][l] * inv_s;
            float dx = zi.x - zj.x, dy = zi.y - zj.y;
            float dsq = dx * dx + dy * dy;
            float arg = 1.0f + 2.0f * dsq / (zi.z * zj.z);
            arg = fmaxf(arg, 1.0f + 1e-7f);
            float dist = acoshf(arg) * scale;
            float d = ham - dist;
            float wgt = (i < j) ? 2.0f : (i == j ? 1.0f : 0.0f);
            local += wgt * d * d;
        }
    }

#pragma unroll
    for (int off = 32; off > 0; off >>= 1) local += __shfl_down(local, off);
    if ((tid & 63) == 0) wsum[tid >> 6] = local;
    __syncthreads();

    if (tid == 0) {
        double part = (double)(wsum[0] + wsum[1] + wsum[2] + wsum[3]);
        atomicAdd(acc, part);                    // device-scope; measured-free (R0)
        __threadfence();
        unsigned prev = atomicAdd(ticket, 1u);
        if (prev == NBLK - 1) {
            double tot = atomicAdd(acc, 0.0);    // coherent read of total
            out[0] = (float)(tot / ((double)N_SEQ * (double)N_SEQ));
        }
    }
}

extern "C" void kernel_launch(void* const* d_in, const int* in_sizes, int n_in,
                              void* d_out, int out_size, void* d_ws, size_t ws_size,
                              hipStream_t stream) {
    const vfloat4* data     = (const vfloat4*)d_in[0]; // N x S x A fp32 one-hot
    const float*  table     = (const float*)d_in[1];   // N x 2
    const float*  log_scale = (const float*)d_in[2];   // scalar
    float* out = (float*)d_out;

    char* ws = (char*)d_ws;
    ulonglong2* codes   = (ulonglong2*)ws;                                   // 2 MB
    float4*     zbuf    = (float4*)(ws + (size_t)N_SEQ * W_SEQ * sizeof(ulonglong2));
    char*       scal    = (char*)zbuf + (size_t)N_SEQ * sizeof(float4);
    double*     acc     = (double*)scal;                                     // 8 B
    unsigned*   done    = (unsigned*)(scal + 8);                             // 33*4 B
    unsigned*   ticket  = (unsigned*)(scal + 8 + (GROUPS + 1) * 4);          // 4 B

    // zero acc + done[33] + ticket (ws is 0xAA-poisoned every call)
    hipMemsetAsync(scal, 0, 8 + (GROUPS + 1) * 4 + 4, stream);

    void* args[] = { (void*)&data, (void*)&table, (void*)&log_scale, (void*)&codes,
                     (void*)&zbuf, (void*)&acc,   (void*)&done,      (void*)&ticket,
                     (void*)&out };
    hipError_t e = hipLaunchCooperativeKernel((const void*)fused_kernel,
                                              dim3(TOTAL_BLK), dim3(256),
                                              args, 0, stream);
    if (e != hipSuccess) {
        // fallback: plain launch — 784 blocks of 256 thr @ 34.8KB LDS, <=128 VGPR
        // -> 4 blocks/CU capacity = 1024 slots >= 784, all co-resident in practice
        fused_kernel<<<TOTAL_BLK, 256, 0, stream>>>(data, table, log_scale, codes,
                                                    zbuf, acc, done, ticket, out);
    }
}

// Round 3
// 230.015 us; speedup vs baseline: 8.7033x; 8.7033x over previous
//
#include <hip/hip_runtime.h>

#define N_SEQ 2048
#define S_LEN 4096
#define W_SEQ 64                               // u64 words per sequence (S/64)
#define TILE 32                                // finer tiles: better CU load balance
#define T_TILES (N_SEQ / TILE)                 // 64
#define NBLK (T_TILES * (T_TILES + 1) / 2)     // 2080 upper-triangle tiles (~8.1/CU)
#define CHUNK 16                               // words per LDS K-chunk
#define STRIDE 17                              // padded LDS row stride (conflict-free)
#define NSITES (N_SEQ * S_LEN)                 // 8388608
#define ENC_BLOCKS 4096
#define ENC_THREADS (ENC_BLOCKS * 256)         // 1048576 -> 8 sites/thread

typedef float vfloat4 __attribute__((ext_vector_type(4)));   // native vec for nontemporal builtin

// ---------------- Kernel 1: encode + zprep ----------------
// one-hot fp32 -> 2-bit packed bit-planes (wave __ballot), plus tiny z-prep.
// HBM-stream-bound: 134 MB read-once at ~6.3 TB/s => ~21-25 us floor.
__global__ __launch_bounds__(256) void encode_kernel(const vfloat4* __restrict__ data,
                                                     const float* __restrict__ table,
                                                     ulonglong2* __restrict__ codes,
                                                     float4* __restrict__ zbuf) {
    int tid = threadIdx.x;
    int gtid = blockIdx.x * 256 + tid;

    if (gtid < N_SEQ) {
        float vx = table[2 * gtid], vy = table[2 * gtid + 1];
        float n = sqrtf(vx * vx + vy * vy);
        float f = tanhf(n) / fmaxf(n, 1e-12f);
        float zx = vx * f, zy = vy * f;
        float omn = 1.0f - (zx * zx + zy * zy);      // 1 - ||z||^2
        zbuf[gtid] = make_float4(zx, zy, omn, 0.0f);
    }

    // grid-stride; stride is a multiple of 64 so each wave maps to one u64 word.
    // tokens: 0->x, 1->y, 2->z, 3->w  =>  lo-plane = y|w, hi-plane = z|w.
#pragma unroll
    for (int it = 0; it < NSITES / ENC_THREADS; ++it) {
        int t = gtid + it * ENC_THREADS;
        vfloat4 v = __builtin_nontemporal_load(&data[t]);   // read-once 134 MB stream
        unsigned long long lo = __ballot(v.y + v.w > 0.5f);
        unsigned long long hi = __ballot(v.z + v.w > 0.5f);
        if ((tid & 63) == 0) {
            ulonglong2 e; e.x = lo; e.y = hi;
            codes[t >> 6] = e;
        }
    }
}

// ---------------- Kernel 2: pairwise popcount-hamming + hyperbolic ----
// 32x32 pair tile per block; 16x16 threads, each owns 2x2 pairs. 2080 blocks
// (~8.1/CU) so the 528-on-256 tail quantization of the old 64-tile version
// (16 CUs carrying 3 heavy tiles, +50% makespan) becomes +~11% worst-case;
// 4 blocks/CU residency lets the scheduler backfill dynamically.
// ATOMIC-FREE epilogue (R2 lesson: cross-XCD sync is poison): partial per
// block to part[bid]; kernel boundary orders it for the reduce.
__global__ __launch_bounds__(256, 4) void pairs_kernel(const ulonglong2* __restrict__ codes,
                                                       const float4* __restrict__ zbuf,
                                                       const float* __restrict__ log_scale,
                                                       double* __restrict__ part) {
    __shared__ ulonglong2 As[TILE * STRIDE];
    __shared__ ulonglong2 Bs[TILE * STRIDE];
    __shared__ float wsum[4];

    int bid = blockIdx.x;
    // triangle mapping: bid = r*(r+1)/2 + c, c <= r (i-tile = c, j-tile = r)
    int r = (int)((sqrtf(8.0f * (float)bid + 1.0f) - 1.0f) * 0.5f);
    while ((r + 1) * (r + 2) / 2 <= bid) ++r;
    while (r * (r + 1) / 2 > bid) --r;
    int c = bid - r * (r + 1) / 2;
    int i0 = c * TILE, j0 = r * TILE;

    int tid = threadIdx.x;
    int tx = tid & 15, ty = tid >> 4;

    // staging: entry e = tid + p*256 -> row = e>>4 (0..31), word = e&15
    int srow = tid >> 4, sw = tid & 15;
    const ulonglong2* gA = codes + (size_t)(i0 + srow) * W_SEQ + sw;
    const ulonglong2* gB = codes + (size_t)(j0 + srow) * W_SEQ + sw;
    ulonglong2* lA = As + srow * STRIDE + sw;
    ulonglong2* lB = Bs + srow * STRIDE + sw;

    int mis[2][2];
#pragma unroll
    for (int k = 0; k < 2; ++k)
#pragma unroll
        for (int l = 0; l < 2; ++l) mis[k][l] = 0;

    for (int cc = 0; cc < W_SEQ / CHUNK; ++cc) {
#pragma unroll
        for (int p = 0; p < 2; ++p) {              // +16 rows per pass, 32 rows total
            lA[p * 16 * STRIDE] = gA[(size_t)(p * 16) * W_SEQ + cc * CHUNK];
            lB[p * 16 * STRIDE] = gB[(size_t)(p * 16) * W_SEQ + cc * CHUNK];
        }
        __syncthreads();
#pragma unroll
        for (int w = 0; w < CHUNK; ++w) {
            ulonglong2 a[2], bb[2];
#pragma unroll
            for (int k = 0; k < 2; ++k) a[k] = As[(ty + 16 * k) * STRIDE + w];
#pragma unroll
            for (int l = 0; l < 2; ++l) bb[l] = Bs[(tx + 16 * l) * STRIDE + w];
#pragma unroll
            for (int k = 0; k < 2; ++k)
#pragma unroll
                for (int l = 0; l < 2; ++l)
                    mis[k][l] += __popcll((a[k].x ^ bb[l].x) | (a[k].y ^ bb[l].y));
        }
        __syncthreads();
    }

    // fused epilogue: exact hamming, hyperbolic dist, symmetry-weighted sq-diff
    float scale = expf(log_scale[0]);
    const float inv_s = 1.0f / (float)S_LEN;
    float local = 0.0f;
#pragma unroll
    for (int k = 0; k < 2; ++k) {
        int i = i0 + ty + 16 * k;
        float4 zi = zbuf[i];
#pragma unroll
        for (int l = 0; l < 2; ++l) {
            int j = j0 + tx + 16 * l;
            float4 zj = zbuf[j];
            float ham = (float)mis[k][l] * inv_s;
            float dx = zi.x - zj.x, dy = zi.y - zj.y;
            float dsq = dx * dx + dy * dy;
            float arg = 1.0f + 2.0f * dsq / (zi.z * zj.z);
            arg = fmaxf(arg, 1.0f + 1e-7f);
            float dist = acoshf(arg) * scale;
            float d = ham - dist;
            float wgt = (i < j) ? 2.0f : (i == j ? 1.0f : 0.0f);
            local += wgt * d * d;
        }
    }

#pragma unroll
    for (int off = 32; off > 0; off >>= 1) local += __shfl_down(local, off);
    if ((tid & 63) == 0) wsum[tid >> 6] = local;
    __syncthreads();

    if (tid == 0)
        part[bid] = (double)(wsum[0] + wsum[1] + wsum[2] + wsum[3]);  // private slot, no RMW
}

// ---------------- Kernel 3: tiny deterministic final reduce ----------------
// 1 block, 64 lanes; sums 2080 doubles (~33 loads/lane). Few us incl. launch.
__global__ __launch_bounds__(64) void reduce_kernel(const double* __restrict__ part,
                                                    float* __restrict__ out) {
    double s = 0.0;
    for (int i = threadIdx.x; i < NBLK; i += 64) s += part[i];
#pragma unroll
    for (int off = 32; off > 0; off >>= 1) s += __shfl_down(s, off);
    if (threadIdx.x == 0)
        out[0] = (float)(s / ((double)N_SEQ * (double)N_SEQ));
}

extern "C" void kernel_launch(void* const* d_in, const int* in_sizes, int n_in,
                              void* d_out, int out_size, void* d_ws, size_t ws_size,
                              hipStream_t stream) {
    const vfloat4* data     = (const vfloat4*)d_in[0]; // N x S x A fp32 one-hot
    const float*  table     = (const float*)d_in[1];   // N x 2
    const float*  log_scale = (const float*)d_in[2];   // scalar
    float* out = (float*)d_out;

    char* ws = (char*)d_ws;
    ulonglong2* codes   = (ulonglong2*)ws;                                       // 2 MB
    float4*     zbuf    = (float4*)(ws + (size_t)N_SEQ * W_SEQ * sizeof(ulonglong2));
    double*     part    = (double*)((char*)zbuf + (size_t)N_SEQ * sizeof(float4));

    encode_kernel<<<ENC_BLOCKS, 256, 0, stream>>>(data, table, codes, zbuf);
    pairs_kernel <<<NBLK,       256, 0, stream>>>(codes, zbuf, log_scale, part);
    reduce_kernel<<<1,          64,  0, stream>>>(part, out);
}